// Round 16
// baseline (59.726 us; speedup 1.0000x reference)
//
#include <hip/hip_runtime.h>
#include <hip/hip_bf16.h>

typedef __attribute__((ext_vector_type(8)))  short v8s;
typedef __attribute__((ext_vector_type(4)))  float v4f;
typedef __attribute__((ext_vector_type(16))) float v16f;
typedef unsigned long long u64;
typedef unsigned short u16;

#define BB 2
#define TT 2048
#define HH 16
#define DD 64

// ---------- helpers ----------

__device__ __forceinline__ unsigned short f2bf(float f) {
    unsigned int u = __builtin_bit_cast(unsigned int, f);
    u = u + 0x7FFFu + ((u >> 16) & 1u);
    return (unsigned short)(u >> 16);
}

__device__ __forceinline__ unsigned cvt2(float a, float b) {
    return ((unsigned)f2bf(b) << 16) | (unsigned)f2bf(a);
}

__device__ __forceinline__ v8s cvt8s(const float4& lo, const float4& hi, float s) {
    union { v8s v; unsigned u[4]; } r;
    r.u[0] = cvt2(lo.x * s, lo.y * s);
    r.u[1] = cvt2(lo.z * s, lo.w * s);
    r.u[2] = cvt2(hi.x * s, hi.y * s);
    r.u[3] = cvt2(hi.z * s, hi.w * s);
    return r.v;
}

// packed f32x2 -> bf16x2 (RNE), S0 -> lo, S1 -> hi
__device__ __forceinline__ unsigned cvtpk(float lo, float hi) {
    unsigned r;
    asm("v_cvt_pk_bf16_f32 %0, %1, %2" : "=v"(r) : "v"(lo), "v"(hi));
    return r;
}

__device__ __forceinline__ v8s pack8(u64 lo, u64 hi) {
    union { v8s v; u64 q[2]; } u;
    u.q[0] = lo; u.q[1] = hi;
    return u.v;
}

typedef __attribute__((address_space(1))) const unsigned int gas_u32;
typedef __attribute__((address_space(3))) unsigned int las_u32;
__device__ __forceinline__ void gl_lds16(const void* g, void* l) {
    __builtin_amdgcn_global_load_lds((gas_u32*)g, (las_u32*)l, 16, 0, 0);
}

// ---------- pre-pass: lane-linear fragment images (unchanged, proven) ----------
// Per (b,h) pair p: 512KB image, 64 tiles (32 kv each) x 8192B:
//   K chunk c (0..3) at tile*8192 + c*1024 + lane*16:
//     {K[32t+al][16c+4hh+0..3], K[32t+al][16c+8+4hh+0..3]}  (al=lane&31, hh=lane>>5)
//   V chunk k=dt*2+cc at tile*8192 + 4096 + k*1024 + lane*16:
//     {V[32t+16cc+4hh+j][32dt+al] j=0..3, V[32t+16cc+8+4hh+j][32dt+al] j=0..3}

__global__ __launch_bounds__(256)
void prep_kv(const float* __restrict__ kvg, char* __restrict__ wsi) {
    __shared__ u16 vlds[64][72];
    const int wg  = blockIdx.x;
    const int x   = wg & 7;            // target XCD (matches attn swizzle)
    const int rr  = wg >> 3;           // 0..127
    const int p   = x * 4 + (rr & 3);  // (b,h) pair
    const int t64 = rr >> 2;           // 64-row region = tiles {2*t64, 2*t64+1}
    const int h   = p & 15;
    const int b   = p >> 4;
    const int t   = threadIdx.x;
    const int s0g = t64 * 64;

    char* obase = wsi + (size_t)p * 524288 + (size_t)t64 * 16384;

    #pragma unroll
    for (int ii = 0; ii < 2; ++ii) {
        int id  = t + 256 * ii;
        int tt2 = id >> 8;
        int al  = (id >> 3) & 31;
        int c   = (id >> 1) & 3;
        int hh  = id & 1;
        const float* kp = kvg + ((((size_t)(b * TT + s0g + 32 * tt2 + al) * 2 + 0) * HH + h) * DD + 16 * c + 4 * hh);
        float4 ka = *(const float4*)kp;
        float4 kb = *(const float4*)(kp + 8);
        *(v8s*)(obase + tt2 * 8192 + c * 1024 + (((hh << 5) | al) << 4)) = cvt8s(ka, kb, 1.0f);
    }
    #pragma unroll
    for (int ii = 0; ii < 2; ++ii) {
        int id  = t + 256 * ii;
        int row = id >> 3;
        int d8  = id & 7;
        const float* vp = kvg + ((((size_t)(b * TT + s0g + row) * 2 + 1) * HH + h) * DD + 8 * d8);
        float4 va = *(const float4*)vp;
        float4 vb = *(const float4*)(vp + 4);
        *(v8s*)&vlds[row][8 * d8] = cvt8s(va, vb, 1.0f);
    }
    __syncthreads();
    #pragma unroll
    for (int ii = 0; ii < 2; ++ii) {
        int id  = t + 256 * ii;
        int tt2 = id >> 8;
        int k   = (id >> 6) & 3;
        int l   = id & 63;
        int dt  = k >> 1, cc = k & 1;
        int al  = l & 31, hh = l >> 5;
        union { v8s v; u16 w[8]; } r;
        #pragma unroll
        for (int j = 0; j < 4; ++j) {
            r.w[j]     = vlds[32 * tt2 + 16 * cc + 4 * hh + j][32 * dt + al];
            r.w[4 + j] = vlds[32 * tt2 + 16 * cc + 8 + 4 * hh + j][32 * dt + al];
        }
        *(v8s*)(obase + tt2 * 8192 + 4096 + k * 1024 + (l << 4)) = r.v;
    }
}

// ---------- attention v14: triple-buffer / ONE barrier per tile + setprio ----
// Same structure & math as v13 (passed, 48.7us). Changes:
//  (1) 3 LDS buffers per kv-group, single barrier per iteration. Skew <= 1
//      barrier; STAGE(i+1) overwrites buf((i-2)%3) whose readers (iter i-1
//      compute) precede barrier-i in program order -> race-free.
//  (2) s_setprio(1) around QK and PV MFMA clusters (T5; stage/compute role
//      diversity exists here).

__global__ __launch_bounds__(256, 2)
void attn_v14(const float* __restrict__ qg, const char* __restrict__ wsi,
              float* __restrict__ outg) {
    __shared__ __align__(16) char smem[49152];   // [g][3 bufs] 8KB; reused for merge

    const int bid  = blockIdx.x;
    const int wgid = (bid & 7) * 128 + (bid >> 3);   // XCD-contiguous (1024 % 8 == 0)
    const int qb   = wgid & 31;        // 32 q-chunks of 64 rows
    const int p    = wgid >> 5;        // (b,h) pair, [4x, 4x+4) on XCD x
    const int hH   = p & 15;
    const int b    = p >> 4;
    const int tid  = threadIdx.x;
    const int lane = tid & 63;
    const int w    = tid >> 6;         // 0..3
    const int g    = w >> 1;           // kv half
    const int sq   = w & 1;            // q subblock
    const int al   = lane & 31;
    const int hh   = lane >> 5;

    const char* kvb = wsi + (size_t)p * 524288;
    const int q0    = qb * 64 + sq * 32;
    const int tbase = g * 32;          // this group's first tile

    // Q fragments (pre-scaled into exp2 domain)
    const float qscale = 0.125f * 1.4426950408889634f;
    v8s qf[4];
    {
        const float* qp = qg + ((size_t)((b * TT + q0 + al) * HH + hH)) * DD;
        #pragma unroll
        for (int c = 0; c < 4; ++c) {
            float4 lo = *(const float4*)(qp + 16 * c + 4 * hh);
            float4 hi = *(const float4*)(qp + 16 * c + 4 * hh + 8);
            qf[c] = cvt8s(lo, hi, qscale);
        }
    }

    char* gbase = smem + g * 24576;

#define STAGE(buf, ii)                                                          \
    do {                                                                        \
        const char* src = kvb + (size_t)(tbase + (ii)) * 8192 + sq * 1024;      \
        char* dst = gbase + (buf) * 8192 + sq * 1024;                           \
        gl_lds16(src + (size_t)lane * 16,        dst);                          \
        gl_lds16(src + 2048 + (size_t)lane * 16, dst + 2048);                   \
        gl_lds16(src + 4096 + (size_t)lane * 16, dst + 4096);                   \
        gl_lds16(src + 6144 + (size_t)lane * 16, dst + 6144);                   \
    } while (0)

    v16f oa[2];
    #pragma unroll
    for (int dt = 0; dt < 2; ++dt)
        #pragma unroll
        for (int r = 0; r < 16; ++r) oa[dt][r] = 0.0f;
    float lsum = 0.0f;

    STAGE(0, 0);

    int cur = 0, nxt = 1;
    for (int i = 0; i < 32; ++i) {
        if (i < 31) {
            STAGE(nxt, i + 1);
            asm volatile("s_waitcnt vmcnt(4)" ::: "memory");
        } else {
            asm volatile("s_waitcnt vmcnt(0)" ::: "memory");
        }
        __builtin_amdgcn_s_barrier();

        const char* tb = gbase + cur * 8192;

        // ---- QK^T (swapped): D col = q (al), row r <-> kv = (r&3)+8*(r>>2)+4hh
        v16f st;
        #pragma unroll
        for (int r = 0; r < 16; ++r) st[r] = 0.0f;
        __builtin_amdgcn_s_setprio(1);
        #pragma unroll
        for (int c = 0; c < 4; ++c) {
            v8s kf = *(const v8s*)(tb + c * 1024 + lane * 16);
            st = __builtin_amdgcn_mfma_f32_32x32x16_bf16(kf, qf[c], st, 0, 0, 0);
        }
        __builtin_amdgcn_s_setprio(0);

        // ---- fixed-base softmax: P = exp2(score), per-lane partial sum ----
        #pragma unroll
        for (int r = 0; r < 16; ++r)
            st[r] = __builtin_amdgcn_exp2f(st[r]);
        {
            float a0 = st[0] + st[1],   a1 = st[2] + st[3];
            float a2 = st[4] + st[5],   a3 = st[6] + st[7];
            float a4 = st[8] + st[9],   a5 = st[10] + st[11];
            float a6 = st[12] + st[13], a7 = st[14] + st[15];
            a0 += a1; a2 += a3; a4 += a5; a6 += a7;
            lsum += (a0 + a2) + (a4 + a6);
        }

        // ---- P -> bf16 B-frags ----
        v8s pf[2];
        #pragma unroll
        for (int cc = 0; cc < 2; ++cc) {
            union { v8s v; unsigned u[4]; } r;
            #pragma unroll
            for (int ww = 0; ww < 4; ++ww)
                r.u[ww] = cvtpk(st[8 * cc + 2 * ww], st[8 * cc + 2 * ww + 1]);
            pf[cc] = r.v;
        }

        // ---- PV: O^T[d][q] += V^T x P^T ----
        __builtin_amdgcn_s_setprio(1);
        #pragma unroll
        for (int cc = 0; cc < 2; ++cc) {
            #pragma unroll
            for (int dt = 0; dt < 2; ++dt) {
                v8s vf = *(const v8s*)(tb + 4096 + (dt * 2 + cc) * 1024 + lane * 16);
                oa[dt] = __builtin_amdgcn_mfma_f32_32x32x16_bf16(vf, pf[cc], oa[dt], 0, 0, 0);
            }
        }
        __builtin_amdgcn_s_setprio(0);

        cur = nxt;
        nxt = (nxt == 2) ? 0 : nxt + 1;
    }

    // fold lsum across the hh pair (once)
    lsum += __shfl_xor(lsum, 32);

    // ---- merge the two kv-half partials (fixed base -> pure add) ----
    __syncthreads();                       // staging done; smem reusable
    float* mg = (float*)smem;              // [sq][64 lanes][33]
    if (g == 1) {
        float* pp = mg + (sq * 64 + lane) * 33;
        #pragma unroll
        for (int dt = 0; dt < 2; ++dt)
            #pragma unroll
            for (int r = 0; r < 16; ++r) pp[dt * 16 + r] = oa[dt][r];
        pp[32] = lsum;
    }
    __syncthreads();
    if (g == 0) {
        const float* pp = mg + (sq * 64 + lane) * 33;
        float li = 1.0f / (lsum + pp[32]);
        const size_t obase = ((size_t)((b * TT + q0 + al) * HH + hH)) * DD;
        #pragma unroll
        for (int dt = 0; dt < 2; ++dt)
            #pragma unroll
            for (int r = 0; r < 16; ++r) {
                int d = 32 * dt + (r & 3) + 8 * (r >> 2) + 4 * hh;
                outg[obase + d] = (oa[dt][r] + pp[dt * 16 + r]) * li;
            }
    }
}

// ---------- fallback v1 (proven, ws-independent) ----------

__global__ __launch_bounds__(256)
void attn_fwd_v1(const float* __restrict__ qg, const float* __restrict__ kvg,
                 float* __restrict__ outg) {
    __shared__ __align__(16) u16 Klds[32][68];
    __shared__ __align__(16) u16 Vt[DD][36];

    const int wg    = blockIdx.x;
    const int qtile = wg & 31;
    const int h     = (wg >> 5) & 15;
    const int b     = wg >> 9;
    const int tid   = threadIdx.x;
    const int lane  = tid & 63;
    const int wid   = tid >> 6;
    const int lr    = lane & 15;
    const int lg    = lane >> 4;
    const int q0    = qtile * 64 + wid * 16;

    const float qscale = 0.125f * 1.4426950408889634f;
    v8s qf[2];
    {
        const float* qb = qg + ((size_t)((b * TT + q0 + lr) * HH + h)) * DD;
        #pragma unroll
        for (int c = 0; c < 2; ++c) {
            float4 lo = *(const float4*)(qb + 32 * c + 4 * lg);
            float4 hi = *(const float4*)(qb + 32 * c + 4 * lg + 16);
            qf[c] = cvt8s(lo, hi, qscale);
        }
    }

    v4f oa[4];
    #pragma unroll
    for (int dc = 0; dc < 4; ++dc)
        #pragma unroll
        for (int r = 0; r < 4; ++r) oa[dc][r] = 0.0f;
    float m = -INFINITY, lsum = 0.0f;

    for (int kv0 = 0; kv0 < TT; kv0 += 32) {
        __syncthreads();
        #pragma unroll
        for (int i = 0; i < 2; ++i) {
            int id  = tid + 256 * i;
            int row = id >> 4;
            int cg  = (id & 15) * 4;
            const float* gp = kvg + ((size_t)(((b * TT + kv0 + row) * 2 + 0) * HH + h)) * DD + cg;
            float4 f = *(const float4*)gp;
            ushort4 w;
            w.x = f2bf(f.x); w.y = f2bf(f.y); w.z = f2bf(f.z); w.w = f2bf(f.w);
            *(ushort4*)&Klds[row][cg] = w;
        }
        {
            int s0 = tid >> 4;
            int dg = (tid & 15) * 4;
            const float* gp0 = kvg + ((size_t)(((b * TT + kv0 + 2 * s0) * 2 + 1) * HH + h)) * DD + dg;
            const float* gp1 = gp0 + 2 * HH * DD;
            float4 fa = *(const float4*)gp0;
            float4 fb = *(const float4*)gp1;
            float av[4] = {fa.x, fa.y, fa.z, fa.w};
            float bv[4] = {fb.x, fb.y, fb.z, fb.w};
            #pragma unroll
            for (int i = 0; i < 4; ++i) {
                ushort2 w;
                w.x = f2bf(av[i]);
                w.y = f2bf(bv[i]);
                *(ushort2*)&Vt[dg + i][2 * s0] = w;
            }
        }
        __syncthreads();

        v4f st0, st1;
        #pragma unroll
        for (int r = 0; r < 4; ++r) { st0[r] = 0.0f; st1[r] = 0.0f; }
        #pragma unroll
        for (int c = 0; c < 2; ++c) {
            {
                u64 lo = *(const u64*)&Klds[lr][32 * c + 4 * lg];
                u64 hi = *(const u64*)&Klds[lr][32 * c + 4 * lg + 16];
                st0 = __builtin_amdgcn_mfma_f32_16x16x32_bf16(pack8(lo, hi), qf[c], st0, 0, 0, 0);
            }
            {
                u64 lo = *(const u64*)&Klds[16 + lr][32 * c + 4 * lg];
                u64 hi = *(const u64*)&Klds[16 + lr][32 * c + 4 * lg + 16];
                st1 = __builtin_amdgcn_mfma_f32_16x16x32_bf16(pack8(lo, hi), qf[c], st1, 0, 0, 0);
            }
        }

        float sc[8] = {st0[0], st0[1], st0[2], st0[3], st1[0], st1[1], st1[2], st1[3]};
        float mc = sc[0];
        #pragma unroll
        for (int i = 1; i < 8; ++i) mc = fmaxf(mc, sc[i]);
        mc = fmaxf(mc, __shfl_xor(mc, 16));
        mc = fmaxf(mc, __shfl_xor(mc, 32));
        float mnew  = fmaxf(m, mc);
        float alpha = __builtin_amdgcn_exp2f(m - mnew);
        float p[8], ps = 0.0f;
        #pragma unroll
        for (int i = 0; i < 8; ++i) { p[i] = __builtin_amdgcn_exp2f(sc[i] - mnew); ps += p[i]; }
        ps += __shfl_xor(ps, 16);
        ps += __shfl_xor(ps, 32);
        lsum = lsum * alpha + ps;
        m = mnew;

        float ar0 = __shfl(alpha, 4 * lg + 0);
        float ar1 = __shfl(alpha, 4 * lg + 1);
        float ar2 = __shfl(alpha, 4 * lg + 2);
        float ar3 = __shfl(alpha, 4 * lg + 3);
        #pragma unroll
        for (int dc = 0; dc < 4; ++dc) {
            oa[dc][0] *= ar0; oa[dc][1] *= ar1; oa[dc][2] *= ar2; oa[dc][3] *= ar3;
        }

        v8s pf;
        #pragma unroll
        for (int i = 0; i < 8; ++i) pf[i] = (short)f2bf(p[i]);

        #pragma unroll
        for (int dc = 0; dc < 4; ++dc) {
            u64 lo = *(const u64*)&Vt[16 * dc + lr][4 * lg];
            u64 hi = *(const u64*)&Vt[16 * dc + lr][4 * lg + 16];
            oa[dc] = __builtin_amdgcn_mfma_f32_16x16x32_bf16(pf, pack8(lo, hi), oa[dc], 0, 0, 0);
        }
    }

    float rl  = 1.0f / lsum;
    float rr0 = __shfl(rl, 4 * lg + 0);
    float rr1 = __shfl(rl, 4 * lg + 1);
    float rr2 = __shfl(rl, 4 * lg + 2);
    float rr3 = __shfl(rl, 4 * lg + 3);
    #pragma unroll
    for (int dc = 0; dc < 4; ++dc) {
        size_t base = ((size_t)((b * TT + q0) * HH + h)) * DD + 16 * dc + lr;
        outg[base + (size_t)(4 * lg + 0) * HH * DD] = oa[dc][0] * rr0;
        outg[base + (size_t)(4 * lg + 1) * HH * DD] = oa[dc][1] * rr1;
        outg[base + (size_t)(4 * lg + 2) * HH * DD] = oa[dc][2] * rr2;
        outg[base + (size_t)(4 * lg + 3) * HH * DD] = oa[dc][3] * rr3;
    }
}

extern "C" void kernel_launch(void* const* d_in, const int* in_sizes, int n_in,
                              void* d_out, int out_size, void* d_ws, size_t ws_size,
                              hipStream_t stream) {
    const float* q  = (const float*)d_in[0];
    const float* kv = (const float*)d_in[1];
    float* out      = (float*)d_out;
    if (ws_size >= (size_t)16777216) {
        char* wsi = (char*)d_ws;
        hipLaunchKernelGGL(prep_kv, dim3(1024), dim3(256), 0, stream, kv, wsi);
        hipLaunchKernelGGL(attn_v14, dim3(1024), dim3(256), 0, stream, q, wsi, out);
    } else {
        hipLaunchKernelGGL(attn_fwd_v1, dim3(1024), dim3(256), 0, stream, q, kv, out);
    }
}

// Round 17
// 53.764 us; speedup vs baseline: 1.1109x; 1.1109x over previous
//
#include <hip/hip_runtime.h>
#include <hip/hip_bf16.h>

typedef __attribute__((ext_vector_type(8)))  short v8s;
typedef __attribute__((ext_vector_type(4)))  float v4f;
typedef __attribute__((ext_vector_type(16))) float v16f;
typedef unsigned long long u64;
typedef unsigned short u16;

#define BB 2
#define TT 2048
#define HH 16
#define DD 64

// ---------- helpers ----------

__device__ __forceinline__ unsigned short f2bf(float f) {
    unsigned int u = __builtin_bit_cast(unsigned int, f);
    u = u + 0x7FFFu + ((u >> 16) & 1u);
    return (unsigned short)(u >> 16);
}

__device__ __forceinline__ unsigned cvt2(float a, float b) {
    return ((unsigned)f2bf(b) << 16) | (unsigned)f2bf(a);
}

__device__ __forceinline__ v8s cvt8s(const float4& lo, const float4& hi, float s) {
    union { v8s v; unsigned u[4]; } r;
    r.u[0] = cvt2(lo.x * s, lo.y * s);
    r.u[1] = cvt2(lo.z * s, lo.w * s);
    r.u[2] = cvt2(hi.x * s, hi.y * s);
    r.u[3] = cvt2(hi.z * s, hi.w * s);
    return r.v;
}

// packed f32x2 -> bf16x2 (RNE), S0 -> lo, S1 -> hi
__device__ __forceinline__ unsigned cvtpk(float lo, float hi) {
    unsigned r;
    asm("v_cvt_pk_bf16_f32 %0, %1, %2" : "=v"(r) : "v"(lo), "v"(hi));
    return r;
}

__device__ __forceinline__ v8s pack8(u64 lo, u64 hi) {
    union { v8s v; u64 q[2]; } u;
    u.q[0] = lo; u.q[1] = hi;
    return u.v;
}

typedef __attribute__((address_space(1))) const unsigned int gas_u32;
typedef __attribute__((address_space(3))) unsigned int las_u32;
__device__ __forceinline__ void gl_lds16(const void* g, void* l) {
    __builtin_amdgcn_global_load_lds((gas_u32*)g, (las_u32*)l, 16, 0, 0);
}

// ---------- pre-pass: lane-linear fragment images (unchanged, proven) ----------
// Per (b,h) pair p: 512KB image, 64 tiles (32 kv each) x 8192B:
//   K chunk c (0..3) at tile*8192 + c*1024 + lane*16:
//     {K[32t+al][16c+4hh+0..3], K[32t+al][16c+8+4hh+0..3]}  (al=lane&31, hh=lane>>5)
//   V chunk k=dt*2+cc at tile*8192 + 4096 + k*1024 + lane*16:
//     {V[32t+16cc+4hh+j][32dt+al] j=0..3, V[32t+16cc+8+4hh+j][32dt+al] j=0..3}

__global__ __launch_bounds__(256)
void prep_kv(const float* __restrict__ kvg, char* __restrict__ wsi) {
    __shared__ u16 vlds[64][72];
    const int wg  = blockIdx.x;
    const int x   = wg & 7;            // target XCD (matches attn swizzle)
    const int rr  = wg >> 3;           // 0..127
    const int p   = x * 4 + (rr & 3);  // (b,h) pair
    const int t64 = rr >> 2;           // 64-row region = tiles {2*t64, 2*t64+1}
    const int h   = p & 15;
    const int b   = p >> 4;
    const int t   = threadIdx.x;
    const int s0g = t64 * 64;

    char* obase = wsi + (size_t)p * 524288 + (size_t)t64 * 16384;

    #pragma unroll
    for (int ii = 0; ii < 2; ++ii) {
        int id  = t + 256 * ii;
        int tt2 = id >> 8;
        int al  = (id >> 3) & 31;
        int c   = (id >> 1) & 3;
        int hh  = id & 1;
        const float* kp = kvg + ((((size_t)(b * TT + s0g + 32 * tt2 + al) * 2 + 0) * HH + h) * DD + 16 * c + 4 * hh);
        float4 ka = *(const float4*)kp;
        float4 kb = *(const float4*)(kp + 8);
        *(v8s*)(obase + tt2 * 8192 + c * 1024 + (((hh << 5) | al) << 4)) = cvt8s(ka, kb, 1.0f);
    }
    #pragma unroll
    for (int ii = 0; ii < 2; ++ii) {
        int id  = t + 256 * ii;
        int row = id >> 3;
        int d8  = id & 7;
        const float* vp = kvg + ((((size_t)(b * TT + s0g + row) * 2 + 1) * HH + h) * DD + 8 * d8);
        float4 va = *(const float4*)vp;
        float4 vb = *(const float4*)(vp + 4);
        *(v8s*)&vlds[row][8 * d8] = cvt8s(va, vb, 1.0f);
    }
    __syncthreads();
    #pragma unroll
    for (int ii = 0; ii < 2; ++ii) {
        int id  = t + 256 * ii;
        int tt2 = id >> 8;
        int k   = (id >> 6) & 3;
        int l   = id & 63;
        int dt  = k >> 1, cc = k & 1;
        int al  = l & 31, hh = l >> 5;
        union { v8s v; u16 w[8]; } r;
        #pragma unroll
        for (int j = 0; j < 4; ++j) {
            r.w[j]     = vlds[32 * tt2 + 16 * cc + 4 * hh + j][32 * dt + al];
            r.w[4 + j] = vlds[32 * tt2 + 16 * cc + 8 + 4 * hh + j][32 * dt + al];
        }
        *(v8s*)(obase + tt2 * 8192 + 4096 + k * 1024 + (l << 4)) = r.v;
    }
}

// ---------- attention v15: v13 skeleton, 4-wave-shared staging ----------------
// Block = 8 waves (512 thr) = 2 kv-half groups x 4 q-subblocks. Each group's
// staged tile feeds 4 waves (v13: 2) -> staging traffic + gl_lds count halve.
// Per-wave math byte-identical to v13 (fixed-base softmax, 32 q-rows,
// 32 tiles). Double buffer, 2 barriers/tile, vmcnt(2). Merge = LDS add.

__global__ __launch_bounds__(512, 4)
void attn_v15(const float* __restrict__ qg, const char* __restrict__ wsi,
              float* __restrict__ outg) {
    __shared__ __align__(16) char smem[33792];   // staging 32KB; merge 33KB (reused)

    const int bid  = blockIdx.x;
    const int wgid = (bid & 7) * 64 + (bid >> 3);    // XCD-contiguous (512 % 8 == 0)
    const int qb   = wgid & 15;        // 16 q-chunks of 128 rows
    const int p    = wgid >> 4;        // (b,h) pair, [4x, 4x+4) on XCD x
    const int hH   = p & 15;
    const int b    = p >> 4;
    const int tid  = threadIdx.x;
    const int lane = tid & 63;
    const int w    = tid >> 6;         // 0..7
    const int g    = w >> 2;           // kv half
    const int sq   = w & 3;            // q subblock 0..3
    const int al   = lane & 31;
    const int hh   = lane >> 5;

    const char* kvb = wsi + (size_t)p * 524288;
    const int q0    = qb * 128 + sq * 32;
    const int tbase = g * 32;          // this group's first tile

    // Q fragments (pre-scaled into exp2 domain)
    const float qscale = 0.125f * 1.4426950408889634f;
    v8s qf[4];
    {
        const float* qp = qg + ((size_t)((b * TT + q0 + al) * HH + hH)) * DD;
        #pragma unroll
        for (int c = 0; c < 4; ++c) {
            float4 lo = *(const float4*)(qp + 16 * c + 4 * hh);
            float4 hi = *(const float4*)(qp + 16 * c + 4 * hh + 8);
            qf[c] = cvt8s(lo, hi, qscale);
        }
    }

    char* gbase = smem + g * 16384;    // [buf 0/1] 8KB each

    // stage tile (tbase+ii): 4 waves x 64 lanes x 2 x 16B = 8KB
#define STAGE(buf, ii)                                                          \
    do {                                                                        \
        const char* src = kvb + (size_t)(tbase + (ii)) * 8192 + sq * 1024;      \
        char* dst = gbase + (buf) * 8192 + sq * 1024;                           \
        gl_lds16(src + (size_t)lane * 16,        dst);                          \
        gl_lds16(src + 4096 + (size_t)lane * 16, dst + 4096);                   \
    } while (0)

    v16f oa[2];
    #pragma unroll
    for (int dt = 0; dt < 2; ++dt)
        #pragma unroll
        for (int r = 0; r < 16; ++r) oa[dt][r] = 0.0f;
    float lsum = 0.0f;

    STAGE(0, 0);

    for (int i = 0; i < 32; ++i) {
        const int cur = i & 1;
        if (i < 31) {
            STAGE(cur ^ 1, i + 1);
            asm volatile("s_waitcnt vmcnt(2)" ::: "memory");
        } else {
            asm volatile("s_waitcnt vmcnt(0)" ::: "memory");
        }
        __builtin_amdgcn_s_barrier();

        const char* tb = gbase + cur * 8192;

        // ---- QK^T (swapped): D col = q (al), row r <-> kv = (r&3)+8*(r>>2)+4hh
        v16f st;
        #pragma unroll
        for (int r = 0; r < 16; ++r) st[r] = 0.0f;
        #pragma unroll
        for (int c = 0; c < 4; ++c) {
            v8s kf = *(const v8s*)(tb + c * 1024 + lane * 16);
            st = __builtin_amdgcn_mfma_f32_32x32x16_bf16(kf, qf[c], st, 0, 0, 0);
        }

        // ---- fixed-base softmax: P = exp2(score), per-lane partial sum ----
        #pragma unroll
        for (int r = 0; r < 16; ++r)
            st[r] = __builtin_amdgcn_exp2f(st[r]);
        {
            float a0 = st[0] + st[1],   a1 = st[2] + st[3];
            float a2 = st[4] + st[5],   a3 = st[6] + st[7];
            float a4 = st[8] + st[9],   a5 = st[10] + st[11];
            float a6 = st[12] + st[13], a7 = st[14] + st[15];
            a0 += a1; a2 += a3; a4 += a5; a6 += a7;
            lsum += (a0 + a2) + (a4 + a6);
        }

        // ---- P -> bf16 B-frags ----
        v8s pf[2];
        #pragma unroll
        for (int cc = 0; cc < 2; ++cc) {
            union { v8s v; unsigned u[4]; } r;
            #pragma unroll
            for (int ww = 0; ww < 4; ++ww)
                r.u[ww] = cvtpk(st[8 * cc + 2 * ww], st[8 * cc + 2 * ww + 1]);
            pf[cc] = r.v;
        }

        // ---- PV: O^T[d][q] += V^T x P^T ----
        #pragma unroll
        for (int cc = 0; cc < 2; ++cc) {
            #pragma unroll
            for (int dt = 0; dt < 2; ++dt) {
                v8s vf = *(const v8s*)(tb + 4096 + (dt * 2 + cc) * 1024 + lane * 16);
                oa[dt] = __builtin_amdgcn_mfma_f32_32x32x16_bf16(vf, pf[cc], oa[dt], 0, 0, 0);
            }
        }

        __builtin_amdgcn_s_barrier();
    }

    // fold lsum across the hh pair (once)
    lsum += __shfl_xor(lsum, 32);

    // ---- merge the two kv-half partials (fixed base -> pure add) ----
    __syncthreads();                       // staging done; smem reusable
    float* mg = (float*)smem;              // [sq 0..3][64 lanes][33]
    if (g == 1) {
        float* pp = mg + (sq * 64 + lane) * 33;
        #pragma unroll
        for (int dt = 0; dt < 2; ++dt)
            #pragma unroll
            for (int r = 0; r < 16; ++r) pp[dt * 16 + r] = oa[dt][r];
        pp[32] = lsum;
    }
    __syncthreads();
    if (g == 0) {
        const float* pp = mg + (sq * 64 + lane) * 33;
        float li = 1.0f / (lsum + pp[32]);
        const size_t obase = ((size_t)((b * TT + q0 + al) * HH + hH)) * DD;
        #pragma unroll
        for (int dt = 0; dt < 2; ++dt)
            #pragma unroll
            for (int r = 0; r < 16; ++r) {
                int d = 32 * dt + (r & 3) + 8 * (r >> 2) + 4 * hh;
                outg[obase + d] = (oa[dt][r] + pp[dt * 16 + r]) * li;
            }
    }
}

// ---------- fallback v1 (proven, ws-independent) ----------

__global__ __launch_bounds__(256)
void attn_fwd_v1(const float* __restrict__ qg, const float* __restrict__ kvg,
                 float* __restrict__ outg) {
    __shared__ __align__(16) u16 Klds[32][68];
    __shared__ __align__(16) u16 Vt[DD][36];

    const int wg    = blockIdx.x;
    const int qtile = wg & 31;
    const int h     = (wg >> 5) & 15;
    const int b     = wg >> 9;
    const int tid   = threadIdx.x;
    const int lane  = tid & 63;
    const int wid   = tid >> 6;
    const int lr    = lane & 15;
    const int lg    = lane >> 4;
    const int q0    = qtile * 64 + wid * 16;

    const float qscale = 0.125f * 1.4426950408889634f;
    v8s qf[2];
    {
        const float* qb = qg + ((size_t)((b * TT + q0 + lr) * HH + h)) * DD;
        #pragma unroll
        for (int c = 0; c < 2; ++c) {
            float4 lo = *(const float4*)(qb + 32 * c + 4 * lg);
            float4 hi = *(const float4*)(qb + 32 * c + 4 * lg + 16);
            qf[c] = cvt8s(lo, hi, qscale);
        }
    }

    v4f oa[4];
    #pragma unroll
    for (int dc = 0; dc < 4; ++dc)
        #pragma unroll
        for (int r = 0; r < 4; ++r) oa[dc][r] = 0.0f;
    float m = -INFINITY, lsum = 0.0f;

    for (int kv0 = 0; kv0 < TT; kv0 += 32) {
        __syncthreads();
        #pragma unroll
        for (int i = 0; i < 2; ++i) {
            int id  = tid + 256 * i;
            int row = id >> 4;
            int cg  = (id & 15) * 4;
            const float* gp = kvg + ((size_t)(((b * TT + kv0 + row) * 2 + 0) * HH + h)) * DD + cg;
            float4 f = *(const float4*)gp;
            ushort4 w;
            w.x = f2bf(f.x); w.y = f2bf(f.y); w.z = f2bf(f.z); w.w = f2bf(f.w);
            *(ushort4*)&Klds[row][cg] = w;
        }
        {
            int s0 = tid >> 4;
            int dg = (tid & 15) * 4;
            const float* gp0 = kvg + ((size_t)(((b * TT + kv0 + 2 * s0) * 2 + 1) * HH + h)) * DD + dg;
            const float* gp1 = gp0 + 2 * HH * DD;
            float4 fa = *(const float4*)gp0;
            float4 fb = *(const float4*)gp1;
            float av[4] = {fa.x, fa.y, fa.z, fa.w};
            float bv[4] = {fb.x, fb.y, fb.z, fb.w};
            #pragma unroll
            for (int i = 0; i < 4; ++i) {
                ushort2 w;
                w.x = f2bf(av[i]);
                w.y = f2bf(bv[i]);
                *(ushort2*)&Vt[dg + i][2 * s0] = w;
            }
        }
        __syncthreads();

        v4f st0, st1;
        #pragma unroll
        for (int r = 0; r < 4; ++r) { st0[r] = 0.0f; st1[r] = 0.0f; }
        #pragma unroll
        for (int c = 0; c < 2; ++c) {
            {
                u64 lo = *(const u64*)&Klds[lr][32 * c + 4 * lg];
                u64 hi = *(const u64*)&Klds[lr][32 * c + 4 * lg + 16];
                st0 = __builtin_amdgcn_mfma_f32_16x16x32_bf16(pack8(lo, hi), qf[c], st0, 0, 0, 0);
            }
            {
                u64 lo = *(const u64*)&Klds[16 + lr][32 * c + 4 * lg];
                u64 hi = *(const u64*)&Klds[16 + lr][32 * c + 4 * lg + 16];
                st1 = __builtin_amdgcn_mfma_f32_16x16x32_bf16(pack8(lo, hi), qf[c], st1, 0, 0, 0);
            }
        }

        float sc[8] = {st0[0], st0[1], st0[2], st0[3], st1[0], st1[1], st1[2], st1[3]};
        float mc = sc[0];
        #pragma unroll
        for (int i = 1; i < 8; ++i) mc = fmaxf(mc, sc[i]);
        mc = fmaxf(mc, __shfl_xor(mc, 16));
        mc = fmaxf(mc, __shfl_xor(mc, 32));
        float mnew  = fmaxf(m, mc);
        float alpha = __builtin_amdgcn_exp2f(m - mnew);
        float p[8], ps = 0.0f;
        #pragma unroll
        for (int i = 0; i < 8; ++i) { p[i] = __builtin_amdgcn_exp2f(sc[i] - mnew); ps += p[i]; }
        ps += __shfl_xor(ps, 16);
        ps += __shfl_xor(ps, 32);
        lsum = lsum * alpha + ps;
        m = mnew;

        float ar0 = __shfl(alpha, 4 * lg + 0);
        float ar1 = __shfl(alpha, 4 * lg + 1);
        float ar2 = __shfl(alpha, 4 * lg + 2);
        float ar3 = __shfl(alpha, 4 * lg + 3);
        #pragma unroll
        for (int dc = 0; dc < 4; ++dc) {
            oa[dc][0] *= ar0; oa[dc][1] *= ar1; oa[dc][2] *= ar2; oa[dc][3] *= ar3;
        }

        v8s pf;
        #pragma unroll
        for (int i = 0; i < 8; ++i) pf[i] = (short)f2bf(p[i]);

        #pragma unroll
        for (int dc = 0; dc < 4; ++dc) {
            u64 lo = *(const u64*)&Vt[16 * dc + lr][4 * lg];
            u64 hi = *(const u64*)&Vt[16 * dc + lr][4 * lg + 16];
            oa[dc] = __builtin_amdgcn_mfma_f32_16x16x32_bf16(pf, pack8(lo, hi), oa[dc], 0, 0, 0);
        }
    }

    float rl  = 1.0f / lsum;
    float rr0 = __shfl(rl, 4 * lg + 0);
    float rr1 = __shfl(rl, 4 * lg + 1);
    float rr2 = __shfl(rl, 4 * lg + 2);
    float rr3 = __shfl(rl, 4 * lg + 3);
    #pragma unroll
    for (int dc = 0; dc < 4; ++dc) {
        size_t base = ((size_t)((b * TT + q0) * HH + h)) * DD + 16 * dc + lr;
        outg[base + (size_t)(4 * lg + 0) * HH * DD] = oa[dc][0] * rr0;
        outg[base + (size_t)(4 * lg + 1) * HH * DD] = oa[dc][1] * rr1;
        outg[base + (size_t)(4 * lg + 2) * HH * DD] = oa[dc][2] * rr2;
        outg[base + (size_t)(4 * lg + 3) * HH * DD] = oa[dc][3] * rr3;
    }
}

extern "C" void kernel_launch(void* const* d_in, const int* in_sizes, int n_in,
                              void* d_out, int out_size, void* d_ws, size_t ws_size,
                              hipStream_t stream) {
    const float* q  = (const float*)d_in[0];
    const float* kv = (const float*)d_in[1];
    float* out      = (float*)d_out;
    if (ws_size >= (size_t)16777216) {
        char* wsi = (char*)d_ws;
        hipLaunchKernelGGL(prep_kv, dim3(1024), dim3(256), 0, stream, kv, wsi);
        hipLaunchKernelGGL(attn_v15, dim3(512), dim3(512), 0, stream, q, wsi, out);
    } else {
        hipLaunchKernelGGL(attn_fwd_v1, dim3(1024), dim3(256), 0, stream, q, kv, out);
    }
}

// Round 18
// 53.397 us; speedup vs baseline: 1.1185x; 1.0069x over previous
//
#include <hip/hip_runtime.h>
#include <hip/hip_bf16.h>

typedef __attribute__((ext_vector_type(8)))  short v8s;
typedef __attribute__((ext_vector_type(4)))  float v4f;
typedef __attribute__((ext_vector_type(16))) float v16f;
typedef unsigned long long u64;
typedef unsigned short u16;

#define BB 2
#define TT 2048
#define HH 16
#define DD 64

// ---------- helpers ----------

__device__ __forceinline__ unsigned short f2bf(float f) {
    unsigned int u = __builtin_bit_cast(unsigned int, f);
    u = u + 0x7FFFu + ((u >> 16) & 1u);
    return (unsigned short)(u >> 16);
}

__device__ __forceinline__ unsigned cvt2(float a, float b) {
    return ((unsigned)f2bf(b) << 16) | (unsigned)f2bf(a);
}

__device__ __forceinline__ v8s cvt8s(const float4& lo, const float4& hi, float s) {
    union { v8s v; unsigned u[4]; } r;
    r.u[0] = cvt2(lo.x * s, lo.y * s);
    r.u[1] = cvt2(lo.z * s, lo.w * s);
    r.u[2] = cvt2(hi.x * s, hi.y * s);
    r.u[3] = cvt2(hi.z * s, hi.w * s);
    return r.v;
}

// packed f32x2 -> bf16x2 (RNE), S0 -> lo, S1 -> hi
__device__ __forceinline__ unsigned cvtpk(float lo, float hi) {
    unsigned r;
    asm("v_cvt_pk_bf16_f32 %0, %1, %2" : "=v"(r) : "v"(lo), "v"(hi));
    return r;
}

__device__ __forceinline__ v8s pack8(u64 lo, u64 hi) {
    union { v8s v; u64 q[2]; } u;
    u.q[0] = lo; u.q[1] = hi;
    return u.v;
}

typedef __attribute__((address_space(1))) const unsigned int gas_u32;
typedef __attribute__((address_space(3))) unsigned int las_u32;
__device__ __forceinline__ void gl_lds16(const void* g, void* l) {
    __builtin_amdgcn_global_load_lds((gas_u32*)g, (las_u32*)l, 16, 0, 0);
}

// ---------- pre-pass: lane-linear fragment images (unchanged, proven) ----------
// Per (b,h) pair p: 512KB image, 64 tiles (32 kv each) x 8192B:
//   K chunk c (0..3) at tile*8192 + c*1024 + lane*16:
//     {K[32t+al][16c+4hh+0..3], K[32t+al][16c+8+4hh+0..3]}  (al=lane&31, hh=lane>>5)
//   V chunk k=dt*2+cc at tile*8192 + 4096 + k*1024 + lane*16:
//     {V[32t+16cc+4hh+j][32dt+al] j=0..3, V[32t+16cc+8+4hh+j][32dt+al] j=0..3}

__global__ __launch_bounds__(256)
void prep_kv(const float* __restrict__ kvg, char* __restrict__ wsi) {
    __shared__ u16 vlds[64][72];
    const int wg  = blockIdx.x;
    const int x   = wg & 7;            // target XCD (matches attn swizzle)
    const int rr  = wg >> 3;           // 0..127
    const int p   = x * 4 + (rr & 3);  // (b,h) pair
    const int t64 = rr >> 2;           // 64-row region = tiles {2*t64, 2*t64+1}
    const int h   = p & 15;
    const int b   = p >> 4;
    const int t   = threadIdx.x;
    const int s0g = t64 * 64;

    char* obase = wsi + (size_t)p * 524288 + (size_t)t64 * 16384;

    #pragma unroll
    for (int ii = 0; ii < 2; ++ii) {
        int id  = t + 256 * ii;
        int tt2 = id >> 8;
        int al  = (id >> 3) & 31;
        int c   = (id >> 1) & 3;
        int hh  = id & 1;
        const float* kp = kvg + ((((size_t)(b * TT + s0g + 32 * tt2 + al) * 2 + 0) * HH + h) * DD + 16 * c + 4 * hh);
        float4 ka = *(const float4*)kp;
        float4 kb = *(const float4*)(kp + 8);
        *(v8s*)(obase + tt2 * 8192 + c * 1024 + (((hh << 5) | al) << 4)) = cvt8s(ka, kb, 1.0f);
    }
    #pragma unroll
    for (int ii = 0; ii < 2; ++ii) {
        int id  = t + 256 * ii;
        int row = id >> 3;
        int d8  = id & 7;
        const float* vp = kvg + ((((size_t)(b * TT + s0g + row) * 2 + 1) * HH + h) * DD + 8 * d8);
        float4 va = *(const float4*)vp;
        float4 vb = *(const float4*)(vp + 4);
        *(v8s*)&vlds[row][8 * d8] = cvt8s(va, vb, 1.0f);
    }
    __syncthreads();
    #pragma unroll
    for (int ii = 0; ii < 2; ++ii) {
        int id  = t + 256 * ii;
        int tt2 = id >> 8;
        int k   = (id >> 6) & 3;
        int l   = id & 63;
        int dt  = k >> 1, cc = k & 1;
        int al  = l & 31, hh = l >> 5;
        union { v8s v; u16 w[8]; } r;
        #pragma unroll
        for (int j = 0; j < 4; ++j) {
            r.w[j]     = vlds[32 * tt2 + 16 * cc + 4 * hh + j][32 * dt + al];
            r.w[4 + j] = vlds[32 * tt2 + 16 * cc + 8 + 4 * hh + j][32 * dt + al];
        }
        *(v8s*)(obase + tt2 * 8192 + 4096 + k * 1024 + (l << 4)) = r.v;
    }
}

// ---------- attention v16: v15 + triple-buffer single-barrier + hoisted zero-C
// Block = 8 waves (512 thr) = 2 kv-half groups x 4 q-subblocks, as v15 (45.5us).
// Changes: (1) 3 LDS buffers/group, ONE barrier per tile (v14-proven pattern;
// here LDS 49KB still fits 2 blocks/CU at 512 thr so no occupancy loss).
// (2) constant zero16 as first QK MFMA's C operand (no per-tile acc init).

__global__ __launch_bounds__(512, 4)
void attn_v16(const float* __restrict__ qg, const char* __restrict__ wsi,
              float* __restrict__ outg) {
    __shared__ __align__(16) char smem[49152];   // [g][3 bufs] 8KB; merge reuses

    const int bid  = blockIdx.x;
    const int wgid = (bid & 7) * 64 + (bid >> 3);    // XCD-contiguous (512 % 8 == 0)
    const int qb   = wgid & 15;        // 16 q-chunks of 128 rows
    const int p    = wgid >> 4;        // (b,h) pair, [4x, 4x+4) on XCD x
    const int hH   = p & 15;
    const int b    = p >> 4;
    const int tid  = threadIdx.x;
    const int lane = tid & 63;
    const int w    = tid >> 6;         // 0..7
    const int g    = w >> 2;           // kv half
    const int sq   = w & 3;            // q subblock 0..3
    const int al   = lane & 31;
    const int hh   = lane >> 5;

    const char* kvb = wsi + (size_t)p * 524288;
    const int q0    = qb * 128 + sq * 32;
    const int tbase = g * 32;          // this group's first tile

    // Q fragments (pre-scaled into exp2 domain)
    const float qscale = 0.125f * 1.4426950408889634f;
    v8s qf[4];
    {
        const float* qp = qg + ((size_t)((b * TT + q0 + al) * HH + hH)) * DD;
        #pragma unroll
        for (int c = 0; c < 4; ++c) {
            float4 lo = *(const float4*)(qp + 16 * c + 4 * hh);
            float4 hi = *(const float4*)(qp + 16 * c + 4 * hh + 8);
            qf[c] = cvt8s(lo, hi, qscale);
        }
    }

    char* gbase = smem + g * 24576;    // [buf 0/1/2] 8KB each

    // stage tile (tbase+ii): 4 waves x 64 lanes x 2 x 16B = 8KB
#define STAGE(buf, ii)                                                          \
    do {                                                                        \
        const char* src = kvb + (size_t)(tbase + (ii)) * 8192 + sq * 1024;      \
        char* dst = gbase + (buf) * 8192 + sq * 1024;                           \
        gl_lds16(src + (size_t)lane * 16,        dst);                          \
        gl_lds16(src + 4096 + (size_t)lane * 16, dst + 4096);                   \
    } while (0)

    v16f oa[2];
    #pragma unroll
    for (int dt = 0; dt < 2; ++dt)
        #pragma unroll
        for (int r = 0; r < 16; ++r) oa[dt][r] = 0.0f;
    float lsum = 0.0f;

    v16f zero16;
    #pragma unroll
    for (int r = 0; r < 16; ++r) zero16[r] = 0.0f;

    STAGE(0, 0);

    int cur = 0, nxt = 1;
    for (int i = 0; i < 32; ++i) {
        if (i < 31) {
            STAGE(nxt, i + 1);
            asm volatile("s_waitcnt vmcnt(2)" ::: "memory");
        } else {
            asm volatile("s_waitcnt vmcnt(0)" ::: "memory");
        }
        __builtin_amdgcn_s_barrier();

        const char* tb = gbase + cur * 8192;

        // ---- QK^T (swapped): D col = q (al), row r <-> kv = (r&3)+8*(r>>2)+4hh
        v16f st;
        {
            v8s kf0 = *(const v8s*)(tb + lane * 16);
            st = __builtin_amdgcn_mfma_f32_32x32x16_bf16(kf0, qf[0], zero16, 0, 0, 0);
        }
        #pragma unroll
        for (int c = 1; c < 4; ++c) {
            v8s kf = *(const v8s*)(tb + c * 1024 + lane * 16);
            st = __builtin_amdgcn_mfma_f32_32x32x16_bf16(kf, qf[c], st, 0, 0, 0);
        }

        // ---- fixed-base softmax: P = exp2(score), per-lane partial sum ----
        #pragma unroll
        for (int r = 0; r < 16; ++r)
            st[r] = __builtin_amdgcn_exp2f(st[r]);
        {
            float a0 = st[0] + st[1],   a1 = st[2] + st[3];
            float a2 = st[4] + st[5],   a3 = st[6] + st[7];
            float a4 = st[8] + st[9],   a5 = st[10] + st[11];
            float a6 = st[12] + st[13], a7 = st[14] + st[15];
            a0 += a1; a2 += a3; a4 += a5; a6 += a7;
            lsum += (a0 + a2) + (a4 + a6);
        }

        // ---- P -> bf16 B-frags ----
        v8s pf[2];
        #pragma unroll
        for (int cc = 0; cc < 2; ++cc) {
            union { v8s v; unsigned u[4]; } r;
            #pragma unroll
            for (int ww = 0; ww < 4; ++ww)
                r.u[ww] = cvtpk(st[8 * cc + 2 * ww], st[8 * cc + 2 * ww + 1]);
            pf[cc] = r.v;
        }

        // ---- PV: O^T[d][q] += V^T x P^T ----
        #pragma unroll
        for (int cc = 0; cc < 2; ++cc) {
            #pragma unroll
            for (int dt = 0; dt < 2; ++dt) {
                v8s vf = *(const v8s*)(tb + 4096 + (dt * 2 + cc) * 1024 + lane * 16);
                oa[dt] = __builtin_amdgcn_mfma_f32_32x32x16_bf16(vf, pf[cc], oa[dt], 0, 0, 0);
            }
        }

        cur = nxt;
        nxt = (nxt == 2) ? 0 : nxt + 1;
    }

    // fold lsum across the hh pair (once)
    lsum += __shfl_xor(lsum, 32);

    // ---- merge the two kv-half partials (fixed base -> pure add) ----
    __syncthreads();                       // staging done; smem reusable
    float* mg = (float*)smem;              // [sq 0..3][64 lanes][33]
    if (g == 1) {
        float* pp = mg + (sq * 64 + lane) * 33;
        #pragma unroll
        for (int dt = 0; dt < 2; ++dt)
            #pragma unroll
            for (int r = 0; r < 16; ++r) pp[dt * 16 + r] = oa[dt][r];
        pp[32] = lsum;
    }
    __syncthreads();
    if (g == 0) {
        const float* pp = mg + (sq * 64 + lane) * 33;
        float li = 1.0f / (lsum + pp[32]);
        const size_t obase = ((size_t)((b * TT + q0 + al) * HH + hH)) * DD;
        #pragma unroll
        for (int dt = 0; dt < 2; ++dt)
            #pragma unroll
            for (int r = 0; r < 16; ++r) {
                int d = 32 * dt + (r & 3) + 8 * (r >> 2) + 4 * hh;
                outg[obase + d] = (oa[dt][r] + pp[dt * 16 + r]) * li;
            }
    }
}

// ---------- fallback v1 (proven, ws-independent) ----------

__global__ __launch_bounds__(256)
void attn_fwd_v1(const float* __restrict__ qg, const float* __restrict__ kvg,
                 float* __restrict__ outg) {
    __shared__ __align__(16) u16 Klds[32][68];
    __shared__ __align__(16) u16 Vt[DD][36];

    const int wg    = blockIdx.x;
    const int qtile = wg & 31;
    const int h     = (wg >> 5) & 15;
    const int b     = wg >> 9;
    const int tid   = threadIdx.x;
    const int lane  = tid & 63;
    const int wid   = tid >> 6;
    const int lr    = lane & 15;
    const int lg    = lane >> 4;
    const int q0    = qtile * 64 + wid * 16;

    const float qscale = 0.125f * 1.4426950408889634f;
    v8s qf[2];
    {
        const float* qb = qg + ((size_t)((b * TT + q0 + lr) * HH + h)) * DD;
        #pragma unroll
        for (int c = 0; c < 2; ++c) {
            float4 lo = *(const float4*)(qb + 32 * c + 4 * lg);
            float4 hi = *(const float4*)(qb + 32 * c + 4 * lg + 16);
            qf[c] = cvt8s(lo, hi, qscale);
        }
    }

    v4f oa[4];
    #pragma unroll
    for (int dc = 0; dc < 4; ++dc)
        #pragma unroll
        for (int r = 0; r < 4; ++r) oa[dc][r] = 0.0f;
    float m = -INFINITY, lsum = 0.0f;

    for (int kv0 = 0; kv0 < TT; kv0 += 32) {
        __syncthreads();
        #pragma unroll
        for (int i = 0; i < 2; ++i) {
            int id  = tid + 256 * i;
            int row = id >> 4;
            int cg  = (id & 15) * 4;
            const float* gp = kvg + ((size_t)(((b * TT + kv0 + row) * 2 + 0) * HH + h)) * DD + cg;
            float4 f = *(const float4*)gp;
            ushort4 w;
            w.x = f2bf(f.x); w.y = f2bf(f.y); w.z = f2bf(f.z); w.w = f2bf(f.w);
            *(ushort4*)&Klds[row][cg] = w;
        }
        {
            int s0 = tid >> 4;
            int dg = (tid & 15) * 4;
            const float* gp0 = kvg + ((size_t)(((b * TT + kv0 + 2 * s0) * 2 + 1) * HH + h)) * DD + dg;
            const float* gp1 = gp0 + 2 * HH * DD;
            float4 fa = *(const float4*)gp0;
            float4 fb = *(const float4*)gp1;
            float av[4] = {fa.x, fa.y, fa.z, fa.w};
            float bv[4] = {fb.x, fb.y, fb.z, fb.w};
            #pragma unroll
            for (int i = 0; i < 4; ++i) {
                ushort2 w;
                w.x = f2bf(av[i]);
                w.y = f2bf(bv[i]);
                *(ushort2*)&Vt[dg + i][2 * s0] = w;
            }
        }
        __syncthreads();

        v4f st0, st1;
        #pragma unroll
        for (int r = 0; r < 4; ++r) { st0[r] = 0.0f; st1[r] = 0.0f; }
        #pragma unroll
        for (int c = 0; c < 2; ++c) {
            {
                u64 lo = *(const u64*)&Klds[lr][32 * c + 4 * lg];
                u64 hi = *(const u64*)&Klds[lr][32 * c + 4 * lg + 16];
                st0 = __builtin_amdgcn_mfma_f32_16x16x32_bf16(pack8(lo, hi), qf[c], st0, 0, 0, 0);
            }
            {
                u64 lo = *(const u64*)&Klds[16 + lr][32 * c + 4 * lg];
                u64 hi = *(const u64*)&Klds[16 + lr][32 * c + 4 * lg + 16];
                st1 = __builtin_amdgcn_mfma_f32_16x16x32_bf16(pack8(lo, hi), qf[c], st1, 0, 0, 0);
            }
        }

        float sc[8] = {st0[0], st0[1], st0[2], st0[3], st1[0], st1[1], st1[2], st1[3]};
        float mc = sc[0];
        #pragma unroll
        for (int i = 1; i < 8; ++i) mc = fmaxf(mc, sc[i]);
        mc = fmaxf(mc, __shfl_xor(mc, 16));
        mc = fmaxf(mc, __shfl_xor(mc, 32));
        float mnew  = fmaxf(m, mc);
        float alpha = __builtin_amdgcn_exp2f(m - mnew);
        float p[8], ps = 0.0f;
        #pragma unroll
        for (int i = 0; i < 8; ++i) { p[i] = __builtin_amdgcn_exp2f(sc[i] - mnew); ps += p[i]; }
        ps += __shfl_xor(ps, 16);
        ps += __shfl_xor(ps, 32);
        lsum = lsum * alpha + ps;
        m = mnew;

        float ar0 = __shfl(alpha, 4 * lg + 0);
        float ar1 = __shfl(alpha, 4 * lg + 1);
        float ar2 = __shfl(alpha, 4 * lg + 2);
        float ar3 = __shfl(alpha, 4 * lg + 3);
        #pragma unroll
        for (int dc = 0; dc < 4; ++dc) {
            oa[dc][0] *= ar0; oa[dc][1] *= ar1; oa[dc][2] *= ar2; oa[dc][3] *= ar3;
        }

        v8s pf;
        #pragma unroll
        for (int i = 0; i < 8; ++i) pf[i] = (short)f2bf(p[i]);

        #pragma unroll
        for (int dc = 0; dc < 4; ++dc) {
            u64 lo = *(const u64*)&Vt[16 * dc + lr][4 * lg];
            u64 hi = *(const u64*)&Vt[16 * dc + lr][4 * lg + 16];
            oa[dc] = __builtin_amdgcn_mfma_f32_16x16x32_bf16(pf, pack8(lo, hi), oa[dc], 0, 0, 0);
        }
    }

    float rl  = 1.0f / lsum;
    float rr0 = __shfl(rl, 4 * lg + 0);
    float rr1 = __shfl(rl, 4 * lg + 1);
    float rr2 = __shfl(rl, 4 * lg + 2);
    float rr3 = __shfl(rl, 4 * lg + 3);
    #pragma unroll
    for (int dc = 0; dc < 4; ++dc) {
        size_t base = ((size_t)((b * TT + q0) * HH + h)) * DD + 16 * dc + lr;
        outg[base + (size_t)(4 * lg + 0) * HH * DD] = oa[dc][0] * rr0;
        outg[base + (size_t)(4 * lg + 1) * HH * DD] = oa[dc][1] * rr1;
        outg[base + (size_t)(4 * lg + 2) * HH * DD] = oa[dc][2] * rr2;
        outg[base + (size_t)(4 * lg + 3) * HH * DD] = oa[dc][3] * rr3;
    }
}

extern "C" void kernel_launch(void* const* d_in, const int* in_sizes, int n_in,
                              void* d_out, int out_size, void* d_ws, size_t ws_size,
                              hipStream_t stream) {
    const float* q  = (const float*)d_in[0];
    const float* kv = (const float*)d_in[1];
    float* out      = (float*)d_out;
    if (ws_size >= (size_t)16777216) {
        char* wsi = (char*)d_ws;
        hipLaunchKernelGGL(prep_kv, dim3(1024), dim3(256), 0, stream, kv, wsi);
        hipLaunchKernelGGL(attn_v16, dim3(512), dim3(512), 0, stream, q, wsi, out);
    } else {
        hipLaunchKernelGGL(attn_fwd_v1, dim3(1024), dim3(256), 0, stream, q, kv, out);
    }
}